// Round 5
// baseline (4590.845 us; speedup 1.0000x reference)
//
#include <hip/hip_runtime.h>

// AttentionRnnBlock: N=16, T=2048, H=512.
// q|k|v = cat(x_t,h_t) @ W?.T + b? ; w=sigmoid(q*k); h' = (1-w)h + w tanh(v)
//
// Persistent cooperative kernel, 256 WGs x 512 threads, 1 WG/CU,
// __launch_bounds__(512,1) => 256-reg budget.
//  - 8 groups x 32 WGs; group g owns batches {2g,2g+1}. Cross-WG data moves
//    via agent-scope (PoC) atomics; ordering via __syncthreads vmcnt drain.
//  - wave wv of WG wm owns rows jA=wm*16+2wv, jB=jA+1; lane owns cat slices
//    x[lane*8,+8) and h[lane*8,+8): 96 pinned weight floats / thread.
//  - PINNING IS FORCED via empty inline-asm "+v" on every weight component:
//    round-2..4 profiles proved the compiler otherwise sinks the loads into
//    the loop (VGPR_Count 80-120 < 96 floats) and re-streams 196 KB/step/CU
//    from L2 (~1.45 us/step — the dominant cost).
//  - h LDS tile is XOR-swizzled (idx4 ^= (idx4>>3)&7): kills the 16-way
//    bank conflict (6.7e7 cycles in round 4) on the lane*32B b128 reads.
#define N_B 16
#define T_S 2048
#define H_D 512
#define TH_F ((size_t)T_S * H_D)
#define NTH ((size_t)N_B * TH_F)
#define NGROUP 8
#define WPG 32
#define THREADS 512

#define PIN4(v) asm volatile("" : "+v"(v.x), "+v"(v.y), "+v"(v.z), "+v"(v.w))

__global__ __launch_bounds__(THREADS, 1) void rnn_persist(
    const float* __restrict__ x,
    const float* __restrict__ hidden,
    const float* __restrict__ Wq, const float* __restrict__ bq,
    const float* __restrict__ Wk, const float* __restrict__ bk,
    const float* __restrict__ Wv, const float* __restrict__ bv,
    float* __restrict__ out,
    int* __restrict__ cnt)
{
    const int tid  = threadIdx.x;
    const int lane = tid & 63;
    const int wv   = tid >> 6;          // wave 0..7
    const int g    = blockIdx.x & 7;    // group
    const int wm   = blockIdx.x >> 3;   // member 0..31
    const int b0 = 2 * g, b1 = 2 * g + 1;
    const int jA = wm * 16 + 2 * wv;

    __shared__ __align__(16) float hs[2][H_D];   // h_t staging (swizzled), 4 KB

    // ---- load + FORCE-PIN weights: [row][mat][c], 8 x-floats + 8 h-floats
    float4 wx[2][3][2], wh[2][3][2];
    #pragma unroll
    for (int r = 0; r < 2; ++r) {
        const int j = jA + r;
        #pragma unroll
        for (int m = 0; m < 3; ++m) {
            const float* W = (m == 0) ? Wq : (m == 1) ? Wk : Wv;
            const float* base = W + (size_t)j * 1024 + lane * 8;
            wx[r][m][0] = *(const float4*)(base);
            wx[r][m][1] = *(const float4*)(base + 4);
            wh[r][m][0] = *(const float4*)(base + 512);
            wh[r][m][1] = *(const float4*)(base + 516);
        }
    }
    #pragma unroll
    for (int r = 0; r < 2; ++r)
        #pragma unroll
        for (int m = 0; m < 3; ++m)
            #pragma unroll
            for (int c = 0; c < 2; ++c) { PIN4(wx[r][m][c]); PIN4(wh[r][m][c]); }

    // writer-lane (lane<4) constants: bit0 = batch, bit1 = row
    const int jw = jA + ((lane >> 1) & 1);
    const int bw = (lane & 1) ? b1 : b0;
    const float bqw = bq[jw], bkw = bk[jw], bvw = bv[jw];
    float ho = hidden[bw * H_D + jw];

    // h staging map: thread -> (batch half, float2 #u), swizzled slot
    const int h_nb  = tid >> 8;
    const int u     = tid & 255;
    const int h_pos = u * 2;                          // logical float offset
    const int sm    = (u >> 1) ^ (((u >> 1) >> 3) & 7);
    float2* hslot   = (float2*)&hs[h_nb][0] + (sm * 2 + (u & 1));
    const int h_b   = h_nb ? b1 : b0;

    // ---- prologue: h_0 -> LDS (swizzled); out[:,0,:] = h_0 (first WG only)
    {
        float v0 = hidden[h_b * H_D + h_pos];
        float v1 = hidden[h_b * H_D + h_pos + 1];
        *hslot = make_float2(v0, v1);
        if (wm == 0) {
            out[(size_t)h_b * TH_F + h_pos]     = v0;
            out[(size_t)h_b * TH_F + h_pos + 1] = v1;
        }
    }
    __syncthreads();

    // x lane-slice pointers (float4 granularity) + first prefetch
    const float4* xb0 = (const float4*)(x + (size_t)b0 * TH_F) + lane * 2;
    const float4* xb1 = (const float4*)(x + (size_t)b1 * TH_F) + lane * 2;
    float4 xv[2][2];
    xv[0][0] = xb0[0]; xv[0][1] = xb0[1];
    xv[1][0] = xb1[0]; xv[1][1] = xb1[1];

    // swizzled read slots for this lane's h float4 pair
    const int s0 = (lane * 2) ^ (((lane * 2) >> 3) & 7);
    const int s1 = s0 ^ 1;

    int* mycnt = cnt + g * 64;

    for (int t = 0; t < T_S; ++t) {
        const bool do_next = (t + 1 < T_S);

        // ---- x-part FMAs (96) — h-independent, hides exchange latency
        float acc[2][3][2];
        #pragma unroll
        for (int r = 0; r < 2; ++r)
            #pragma unroll
            for (int m = 0; m < 3; ++m)
                #pragma unroll
                for (int nb = 0; nb < 2; ++nb) acc[r][m][nb] = 0.f;

        #pragma unroll
        for (int nb = 0; nb < 2; ++nb) {
            const float4 a0 = nb ? xv[1][0] : xv[0][0];
            const float4 a1 = nb ? xv[1][1] : xv[0][1];
            #pragma unroll
            for (int r = 0; r < 2; ++r)
                #pragma unroll
                for (int m = 0; m < 3; ++m) {
                    float s = acc[r][m][nb];
                    s = fmaf(wx[r][m][0].x, a0.x, s);
                    s = fmaf(wx[r][m][0].y, a0.y, s);
                    s = fmaf(wx[r][m][0].z, a0.z, s);
                    s = fmaf(wx[r][m][0].w, a0.w, s);
                    s = fmaf(wx[r][m][1].x, a1.x, s);
                    s = fmaf(wx[r][m][1].y, a1.y, s);
                    s = fmaf(wx[r][m][1].z, a1.z, s);
                    s = fmaf(wx[r][m][1].w, a1.w, s);
                    acc[r][m][nb] = s;
                }
        }

        // ---- prefetch x_{t+1} (in flight across the wait)
        if (do_next) {
            const size_t o = (size_t)(t + 1) * 128;
            xv[0][0] = xb0[o]; xv[0][1] = xb0[o + 1];
            xv[1][0] = xb1[o]; xv[1][1] = xb1[o + 1];
        }

        // ---- wait for h_t, stage into LDS (t>=1; t=0 staged in prologue)
        if (t > 0) {
            if (tid == 0) {
                const int target = WPG * t;
                while (__hip_atomic_load(mycnt, __ATOMIC_RELAXED,
                                         __HIP_MEMORY_SCOPE_AGENT) < target) {}
            }
            __syncthreads();
            const float* hsrc = out + (size_t)h_b * TH_F + (size_t)t * H_D + h_pos;
            float v0 = __hip_atomic_load(hsrc,     __ATOMIC_RELAXED, __HIP_MEMORY_SCOPE_AGENT);
            float v1 = __hip_atomic_load(hsrc + 1, __ATOMIC_RELAXED, __HIP_MEMORY_SCOPE_AGENT);
            *hslot = make_float2(v0, v1);
            __syncthreads();
        }

        // ---- h-part FMAs (96), swizzled conflict-free LDS reads
        #pragma unroll
        for (int nb = 0; nb < 2; ++nb) {
            const float4* h4 = (const float4*)&hs[nb][0];
            const float4 a0 = h4[s0];
            const float4 a1 = h4[s1];
            #pragma unroll
            for (int r = 0; r < 2; ++r)
                #pragma unroll
                for (int m = 0; m < 3; ++m) {
                    float s = acc[r][m][nb];
                    s = fmaf(wh[r][m][0].x, a0.x, s);
                    s = fmaf(wh[r][m][0].y, a0.y, s);
                    s = fmaf(wh[r][m][0].z, a0.z, s);
                    s = fmaf(wh[r][m][0].w, a0.w, s);
                    s = fmaf(wh[r][m][1].x, a1.x, s);
                    s = fmaf(wh[r][m][1].y, a1.y, s);
                    s = fmaf(wh[r][m][1].z, a1.z, s);
                    s = fmaf(wh[r][m][1].w, a1.w, s);
                    acc[r][m][nb] = s;
                }
        }

        // ---- split-butterfly reduce: 21 shfl instead of 72
        const bool lb0 = (lane & 1) != 0;   // batch bit
        const bool lb1 = (lane & 2) != 0;   // row bit
        float a6[2][3];
        #pragma unroll
        for (int r = 0; r < 2; ++r)
            #pragma unroll
            for (int m = 0; m < 3; ++m) {
                float keep = lb0 ? acc[r][m][1] : acc[r][m][0];
                float send = lb0 ? acc[r][m][0] : acc[r][m][1];
                a6[r][m] = keep + __shfl_xor(send, 1);
            }
        float a3[3];
        #pragma unroll
        for (int m = 0; m < 3; ++m) {
            float keep = lb1 ? a6[1][m] : a6[0][m];
            float send = lb1 ? a6[0][m] : a6[1][m];
            a3[m] = keep + __shfl_xor(send, 2);
        }
        #pragma unroll
        for (int s = 4; s < 64; s <<= 1) {
            a3[0] += __shfl_xor(a3[0], s);
            a3[1] += __shfl_xor(a3[1], s);
            a3[2] += __shfl_xor(a3[2], s);
        }

        // ---- gate + h_{t+1} store (writer lanes 0..3)
        if (lane < 4) {
            const float q = a3[0] + bqw;
            const float k = a3[1] + bkw;
            const float v = a3[2] + bvw;
            const float e  = __expf(-q * k);
            const float w  = __builtin_amdgcn_rcpf(1.f + e);
            const float ev = __expf(2.f * v);
            const float th = 1.f - 2.f * __builtin_amdgcn_rcpf(ev + 1.f);
            const float hn = fmaf(w, th - ho, ho);
            const size_t opos = do_next
                ? ((size_t)bw * TH_F + (size_t)(t + 1) * H_D + jw)
                : (NTH + (size_t)bw * H_D + jw);            // h_final tail
            __hip_atomic_store(out + opos, hn, __ATOMIC_RELAXED,
                               __HIP_MEMORY_SCOPE_AGENT);
            ho = hn;
        }

        // ---- signal: all 8 waves' stores drained (barrier), then +1
        __syncthreads();
        if (do_next && tid == 0)
            __hip_atomic_fetch_add(mycnt, 1, __ATOMIC_RELAXED,
                                   __HIP_MEMORY_SCOPE_AGENT);
    }
}

extern "C" void kernel_launch(void* const* d_in, const int* in_sizes, int n_in,
                              void* d_out, int out_size, void* d_ws, size_t ws_size,
                              hipStream_t stream) {
    const float* x      = (const float*)d_in[0];
    const float* hidden = (const float*)d_in[1];
    const float* Wq     = (const float*)d_in[2];
    const float* bq     = (const float*)d_in[3];
    const float* Wk     = (const float*)d_in[4];
    const float* bk     = (const float*)d_in[5];
    const float* Wv     = (const float*)d_in[6];
    const float* bv     = (const float*)d_in[7];
    float* out = (float*)d_out;
    int*   cnt = (int*)d_ws;   // 8 counters, 256B stride

    hipMemsetAsync(cnt, 0, 16 * 64 * sizeof(int), stream);

    void* args[] = { (void*)&x, (void*)&hidden,
                     (void*)&Wq, (void*)&bq, (void*)&Wk, (void*)&bk,
                     (void*)&Wv, (void*)&bv, (void*)&out, (void*)&cnt };
    hipLaunchCooperativeKernel((const void*)rnn_persist,
                               dim3(NGROUP * WPG), dim3(THREADS),
                               args, 0, stream);
}

// Round 6
// 4487.584 us; speedup vs baseline: 1.0230x; 1.0230x over previous
//
#include <hip/hip_runtime.h>

// AttentionRnnBlock: N=16, T=2048, H=512.
// q|k|v = cat(x_t,h_t) @ W?.T + b? ; w=sigmoid(q*k); h' = (1-w)h + w tanh(v)
//
// Persistent cooperative kernel, 256 WGs x 512 threads, 1 WG/CU.
//  - 8 groups x 32 WGs; group g owns batches {2g,2g+1}. Cross-WG data moves
//    via agent-scope (PoC) atomics; ordering via __syncthreads vmcnt drain.
//  - wave wv of WG wm owns rows jA=wm*16+2wv, jB=jA+1; lane owns cat slices
//    x[lane*8,+8) and h[lane*8,+8): 96 weight floats / thread.
//  - WEIGHTS LIVE IN AGPRs, loaded once and stashed via explicit
//    v_accvgpr_write_b32 ("a" constraint). Rounds 2-5 proved the register
//    allocator spills source-level "pinned" weights (VGPR_Count 80-120 < 96
//    floats) and re-streams ~196 KB/step/CU through L2/L3 (~1.45 us/step,
//    the dominant cost). AGPR-class values defined/used only by asm cannot
//    be rematerialized or spilled. Per-step cost: 96 v_accvgpr_read VALU ops
//    (~384 cyc/SIMD) vs ~3500 cyc streaming removed.
//  - LDS bank conflicts (2^26 total, 128 cyc/WG/step) are the structural
//    minimum of 8B/lane writes — measured identical across two different
//    swizzles in rounds 4/5; ignored.
#define N_B 16
#define T_S 2048
#define H_D 512
#define TH_F ((size_t)T_S * H_D)
#define NTH ((size_t)N_B * TH_F)
#define NGROUP 8
#define WPG 32
#define THREADS 512

#define STASH(dst, src) asm volatile("v_accvgpr_write_b32 %0, %1" : "=a"(dst) : "v"(src))
#define FETCH(dst, src) asm volatile("v_accvgpr_read_b32 %0, %1" : "=v"(dst) : "a"(src))

__global__ __launch_bounds__(THREADS, 1) void rnn_persist(
    const float* __restrict__ x,
    const float* __restrict__ hidden,
    const float* __restrict__ Wq, const float* __restrict__ bq,
    const float* __restrict__ Wk, const float* __restrict__ bk,
    const float* __restrict__ Wv, const float* __restrict__ bv,
    float* __restrict__ out,
    int* __restrict__ cnt)
{
    const int tid  = threadIdx.x;
    const int lane = tid & 63;
    const int wv   = tid >> 6;          // wave 0..7
    const int g    = blockIdx.x & 7;    // group
    const int wm   = blockIdx.x >> 3;   // member 0..31
    const int b0 = 2 * g, b1 = 2 * g + 1;
    const int jA = wm * 16 + 2 * wv;

    __shared__ __align__(16) float hs[2][H_D];   // h_t staging, 4 KB

    // ---- load weights once, stash all 96 floats into AGPRs
    float awx[2][3][8], awh[2][3][8];
    #pragma unroll
    for (int r = 0; r < 2; ++r) {
        const int j = jA + r;
        #pragma unroll
        for (int m = 0; m < 3; ++m) {
            const float* W = (m == 0) ? Wq : (m == 1) ? Wk : Wv;
            const float* base = W + (size_t)j * 1024 + lane * 8;
            float4 x0 = *(const float4*)(base);
            float4 x1 = *(const float4*)(base + 4);
            float4 h0 = *(const float4*)(base + 512);
            float4 h1 = *(const float4*)(base + 516);
            STASH(awx[r][m][0], x0.x); STASH(awx[r][m][1], x0.y);
            STASH(awx[r][m][2], x0.z); STASH(awx[r][m][3], x0.w);
            STASH(awx[r][m][4], x1.x); STASH(awx[r][m][5], x1.y);
            STASH(awx[r][m][6], x1.z); STASH(awx[r][m][7], x1.w);
            STASH(awh[r][m][0], h0.x); STASH(awh[r][m][1], h0.y);
            STASH(awh[r][m][2], h0.z); STASH(awh[r][m][3], h0.w);
            STASH(awh[r][m][4], h1.x); STASH(awh[r][m][5], h1.y);
            STASH(awh[r][m][6], h1.z); STASH(awh[r][m][7], h1.w);
        }
    }

    // writer-lane (lane<4) constants: bit0 = batch, bit1 = row
    const int jw = jA + ((lane >> 1) & 1);
    const int bw = (lane & 1) ? b1 : b0;
    const float bqw = bq[jw], bkw = bk[jw], bvw = bv[jw];
    float ho = hidden[bw * H_D + jw];

    // h staging map: thread -> (batch half, float2 #u)
    const int h_nb  = tid >> 8;
    const int u     = tid & 255;
    const int h_pos = u * 2;
    const int h_b   = h_nb ? b1 : b0;

    // ---- prologue: h_0 -> LDS; out[:,0,:] = h_0 (group's first WG only)
    {
        float v0 = hidden[h_b * H_D + h_pos];
        float v1 = hidden[h_b * H_D + h_pos + 1];
        *(float2*)&hs[h_nb][h_pos] = make_float2(v0, v1);
        if (wm == 0) {
            out[(size_t)h_b * TH_F + h_pos]     = v0;
            out[(size_t)h_b * TH_F + h_pos + 1] = v1;
        }
    }
    __syncthreads();

    // x lane-slice pointers (float4 granularity) + first prefetch
    const float4* xb0 = (const float4*)(x + (size_t)b0 * TH_F) + lane * 2;
    const float4* xb1 = (const float4*)(x + (size_t)b1 * TH_F) + lane * 2;
    float ax[2][8];
    {
        float4 a = xb0[0], b = xb0[1], c = xb1[0], d = xb1[1];
        ax[0][0]=a.x; ax[0][1]=a.y; ax[0][2]=a.z; ax[0][3]=a.w;
        ax[0][4]=b.x; ax[0][5]=b.y; ax[0][6]=b.z; ax[0][7]=b.w;
        ax[1][0]=c.x; ax[1][1]=c.y; ax[1][2]=c.z; ax[1][3]=c.w;
        ax[1][4]=d.x; ax[1][5]=d.y; ax[1][6]=d.z; ax[1][7]=d.w;
    }

    int* mycnt = cnt + g * 64;

    for (int t = 0; t < T_S; ++t) {
        const bool do_next = (t + 1 < T_S);

        // ---- x-part: 48 AGPR fetches + 96 FMAs — h-independent, runs
        //      before the group wait to hide exchange latency
        float acc[2][3][2];
        #pragma unroll
        for (int r = 0; r < 2; ++r)
            #pragma unroll
            for (int m = 0; m < 3; ++m) {
                float wreg[8];
                #pragma unroll
                for (int c = 0; c < 8; ++c) FETCH(wreg[c], awx[r][m][c]);
                float s0 = 0.f, s1 = 0.f;
                #pragma unroll
                for (int c = 0; c < 8; ++c) {
                    s0 = fmaf(wreg[c], ax[0][c], s0);
                    s1 = fmaf(wreg[c], ax[1][c], s1);
                }
                acc[r][m][0] = s0; acc[r][m][1] = s1;
            }

        // ---- prefetch x_{t+1} (in flight across the wait)
        if (do_next) {
            const size_t o = (size_t)(t + 1) * 128;
            float4 a = xb0[o], b = xb0[o + 1], c = xb1[o], d = xb1[o + 1];
            ax[0][0]=a.x; ax[0][1]=a.y; ax[0][2]=a.z; ax[0][3]=a.w;
            ax[0][4]=b.x; ax[0][5]=b.y; ax[0][6]=b.z; ax[0][7]=b.w;
            ax[1][0]=c.x; ax[1][1]=c.y; ax[1][2]=c.z; ax[1][3]=c.w;
            ax[1][4]=d.x; ax[1][5]=d.y; ax[1][6]=d.z; ax[1][7]=d.w;
        }

        // ---- wait for h_t, stage into LDS (t>=1; t=0 staged in prologue)
        if (t > 0) {
            if (tid == 0) {
                const int target = WPG * t;
                while (__hip_atomic_load(mycnt, __ATOMIC_RELAXED,
                                         __HIP_MEMORY_SCOPE_AGENT) < target) {}
            }
            __syncthreads();
            const unsigned long long* hsrc =
                (const unsigned long long*)(out + (size_t)h_b * TH_F + (size_t)t * H_D) + u;
            unsigned long long raw =
                __hip_atomic_load(hsrc, __ATOMIC_RELAXED, __HIP_MEMORY_SCOPE_AGENT);
            union { unsigned long long q; float2 f; } cv; cv.q = raw;
            *(float2*)&hs[h_nb][h_pos] = cv.f;
            __syncthreads();
        }

        // ---- h-part: 48 AGPR fetches + 96 FMAs
        float hbv[2][8];
        #pragma unroll
        for (int nb = 0; nb < 2; ++nb) {
            const float4* hp = (const float4*)&hs[nb][0] + lane * 2;
            float4 a0 = hp[0], a1 = hp[1];
            hbv[nb][0]=a0.x; hbv[nb][1]=a0.y; hbv[nb][2]=a0.z; hbv[nb][3]=a0.w;
            hbv[nb][4]=a1.x; hbv[nb][5]=a1.y; hbv[nb][6]=a1.z; hbv[nb][7]=a1.w;
        }
        #pragma unroll
        for (int r = 0; r < 2; ++r)
            #pragma unroll
            for (int m = 0; m < 3; ++m) {
                float wreg[8];
                #pragma unroll
                for (int c = 0; c < 8; ++c) FETCH(wreg[c], awh[r][m][c]);
                float s0 = acc[r][m][0], s1 = acc[r][m][1];
                #pragma unroll
                for (int c = 0; c < 8; ++c) {
                    s0 = fmaf(wreg[c], hbv[0][c], s0);
                    s1 = fmaf(wreg[c], hbv[1][c], s1);
                }
                acc[r][m][0] = s0; acc[r][m][1] = s1;
            }

        // ---- split-butterfly reduce: 21 shfl instead of 72
        const bool lb0 = (lane & 1) != 0;   // batch bit
        const bool lb1 = (lane & 2) != 0;   // row bit
        float a6[2][3];
        #pragma unroll
        for (int r = 0; r < 2; ++r)
            #pragma unroll
            for (int m = 0; m < 3; ++m) {
                float keep = lb0 ? acc[r][m][1] : acc[r][m][0];
                float send = lb0 ? acc[r][m][0] : acc[r][m][1];
                a6[r][m] = keep + __shfl_xor(send, 1);
            }
        float a3[3];
        #pragma unroll
        for (int m = 0; m < 3; ++m) {
            float keep = lb1 ? a6[1][m] : a6[0][m];
            float send = lb1 ? a6[0][m] : a6[1][m];
            a3[m] = keep + __shfl_xor(send, 2);
        }
        #pragma unroll
        for (int s = 4; s < 64; s <<= 1) {
            a3[0] += __shfl_xor(a3[0], s);
            a3[1] += __shfl_xor(a3[1], s);
            a3[2] += __shfl_xor(a3[2], s);
        }

        // ---- gate + h_{t+1} store (writer lanes 0..3)
        if (lane < 4) {
            const float q = a3[0] + bqw;
            const float k = a3[1] + bkw;
            const float v = a3[2] + bvw;
            const float e  = __expf(-q * k);
            const float w  = __builtin_amdgcn_rcpf(1.f + e);
            const float ev = __expf(2.f * v);
            const float th = 1.f - 2.f * __builtin_amdgcn_rcpf(ev + 1.f);
            const float hn = fmaf(w, th - ho, ho);
            const size_t opos = do_next
                ? ((size_t)bw * TH_F + (size_t)(t + 1) * H_D + jw)
                : (NTH + (size_t)bw * H_D + jw);            // h_final tail
            __hip_atomic_store(out + opos, hn, __ATOMIC_RELAXED,
                               __HIP_MEMORY_SCOPE_AGENT);
            ho = hn;
        }

        // ---- signal: all 8 waves' stores drained (barrier), then +1
        __syncthreads();
        if (do_next && tid == 0)
            __hip_atomic_fetch_add(mycnt, 1, __ATOMIC_RELAXED,
                                   __HIP_MEMORY_SCOPE_AGENT);
    }
}

extern "C" void kernel_launch(void* const* d_in, const int* in_sizes, int n_in,
                              void* d_out, int out_size, void* d_ws, size_t ws_size,
                              hipStream_t stream) {
    const float* x      = (const float*)d_in[0];
    const float* hidden = (const float*)d_in[1];
    const float* Wq     = (const float*)d_in[2];
    const float* bq     = (const float*)d_in[3];
    const float* Wk     = (const float*)d_in[4];
    const float* bk     = (const float*)d_in[5];
    const float* Wv     = (const float*)d_in[6];
    const float* bv     = (const float*)d_in[7];
    float* out = (float*)d_out;
    int*   cnt = (int*)d_ws;   // 8 counters, 256B stride

    hipMemsetAsync(cnt, 0, 16 * 64 * sizeof(int), stream);

    void* args[] = { (void*)&x, (void*)&hidden,
                     (void*)&Wq, (void*)&bq, (void*)&Wk, (void*)&bk,
                     (void*)&Wv, (void*)&bv, (void*)&out, (void*)&cnt };
    hipLaunchCooperativeKernel((const void*)rnn_persist,
                               dim3(NGROUP * WPG), dim3(THREADS),
                               args, 0, stream);
}